// Round 18
// baseline (259.236 us; speedup 1.0000x reference)
//
#include <hip/hip_runtime.h>

// VQ quantizer: N=65536 rows (D=64) vs K=4096 codes. d_out = FLOAT32
// [x_quantized N*D][indices N][loss 1].
//
// Round-18: R17 + ONE change: MFMAC's 6-deep dependent MFMA chain split into
// two independent 3-chains (accA/accB) + f32 combine in VALUU. Tests the
// dep-latency theory (per-wave-tile cost pinned at ~1200 cyc across R9/R14/R17
// regardless of occupancy/staging => intra-wave chain latency suspected).
// Regrouping error ~3e-8 << margin budget. All else identical to R17 (PASS).

#define D  64

typedef unsigned short u16;
typedef short bf16x8 __attribute__((ext_vector_type(8)));
typedef float f32x4  __attribute__((ext_vector_type(4)));

#define VMWAIT_(n) asm volatile("s_waitcnt vmcnt(" #n ")" ::: "memory")
#define VMWAIT(n) VMWAIT_(n)

__device__ __forceinline__ u16 f32_to_bf16_raw(float f) {
    union { float f; unsigned u; } v; v.f = f;
    unsigned u = v.u;
    u += 0x7FFFu + ((u >> 16) & 1u);   // RNE
    return (u16)(u >> 16);
}
__device__ __forceinline__ float bf16_raw_to_f32(u16 h) {
    union { unsigned u; float f; } v; v.u = ((unsigned)h) << 16;
    return v.f;
}
__device__ __forceinline__ f32x4 mfma16(bf16x8 a, bf16x8 b, f32x4 c) {
    return __builtin_amdgcn_mfma_f32_16x16x32_bf16(a, b, c, 0, 0, 0);
}

// ---------- numpy-exact row sum of squares (pairwise n=64), proven R3 ----------
__device__ __forceinline__ float np_pairwise_sumsq_64(const float* p) {
    float r[8];
    #pragma unroll
    for (int j = 0; j < 8; ++j) r[j] = __fmul_rn(p[j], p[j]);
    #pragma unroll
    for (int i = 8; i < 64; i += 8) {
        #pragma unroll
        for (int j = 0; j < 8; ++j)
            r[j] = __fadd_rn(r[j], __fmul_rn(p[i + j], p[i + j]));
    }
    float t0 = __fadd_rn(r[0], r[1]);
    float t1 = __fadd_rn(r[2], r[3]);
    float t2 = __fadd_rn(r[4], r[5]);
    float t3 = __fadd_rn(r[6], r[7]);
    return __fadd_rn(__fadd_rn(t0, t1), __fadd_rn(t2, t3));
}

// ---------- fused prep: rowsumsq(x|cb) + pack + amb_cnt zeroing ----------
__global__ __launch_bounds__(256) void prep_kernel(const float* __restrict__ x,
                                                   const float* __restrict__ cb,
                                                   float* __restrict__ sx,
                                                   float* __restrict__ sc,
                                                   bf16x8* __restrict__ cbf,
                                                   int* __restrict__ amb_cnt) {
    int b = blockIdx.x;
    if (b == 0 && threadIdx.x == 0) *amb_cnt = 0;
    if (b < 272) {
        const float* a = (b < 256) ? x : cb;
        float* o = (b < 256) ? sx : sc;
        int r0 = (b < 256) ? b * 256 : (b - 256) * 256;
        int r = r0 + threadIdx.x;
        float buf[64];
        const float4* p = (const float4*)(a + (size_t)r * D);
        #pragma unroll
        for (int i = 0; i < 16; ++i) {
            float4 v = p[i];
            buf[4*i] = v.x; buf[4*i+1] = v.y; buf[4*i+2] = v.z; buf[4*i+3] = v.w;
        }
        o[r] = np_pairwise_sumsq_64(buf);
    } else {
        // pack codebook tile t: head/tail bf16 fragments (layout proven R5)
        int t = b - 272;
        int tid = threadIdx.x;
        int lane = tid & 63;
        int ks = (tid >> 6) & 1;
        int hl = tid >> 7;
        int code = t * 16 + (lane & 15);
        int g = lane >> 4;
        bf16x8 v;
        #pragma unroll
        for (int j = 0; j < 8; ++j) {
            int d = ks * 32 + g * 4 + (j & 3) + 16 * (j >> 2);
            float val = cb[(size_t)code * D + d];
            u16 h = f32_to_bf16_raw(val);
            if (hl) {
                float resid = val - bf16_raw_to_f32(h);   // exact (Sterbenz)
                h = f32_to_bf16_raw(resid);
            }
            v[j] = (short)h;
        }
        cbf[((size_t)t * 4 + hl * 2 + ks) * 64 + lane] = v;
    }
}

// ---------- phase 1: swapped-operand split-bf16 MFMA, top-2 on t-scores ----------
#define MARG_A 1.6e-5f
#define MARG_B 6.5e-7f

#define STAGE(T, BUF) do {                                                    \
    const char* _src = (const char*)cbf + (size_t)(T) * 4096 + lane * 16;     \
    char* _dst = ringbase + (BUF) * 4096 + lane * 16;                         \
    __builtin_amdgcn_global_load_lds((const __attribute__((address_space(1))) unsigned int*)(_src),        (__attribute__((address_space(3))) unsigned int*)(_dst),        16, 0, 0); \
    __builtin_amdgcn_global_load_lds((const __attribute__((address_space(1))) unsigned int*)(_src + 1024), (__attribute__((address_space(3))) unsigned int*)(_dst + 1024), 16, 0, 0); \
    __builtin_amdgcn_global_load_lds((const __attribute__((address_space(1))) unsigned int*)(_src + 2048), (__attribute__((address_space(3))) unsigned int*)(_dst + 2048), 16, 0, 0); \
    __builtin_amdgcn_global_load_lds((const __attribute__((address_space(1))) unsigned int*)(_src + 3072), (__attribute__((address_space(3))) unsigned int*)(_dst + 3072), 16, 0, 0); \
} while (0)

#define DSREAD(BUF) do {                                                      \
    const bf16x8* _bfr = (const bf16x8*)(ringbase + (BUF) * 4096);            \
    Fb0h = _bfr[lane]; Fb1h = _bfr[64 + lane];                                \
    Fb0l = _bfr[128 + lane]; Fb1l = _bfr[192 + lane];                         \
} while (0)

// 4 subtiles x TWO independent 3-MFMA chains (dep-latency fix). Same product
// set as R5..R17; accA+accB combined in VALUU (regroup error ~3e-8).
#define MFMAC() do {                                                          \
    _Pragma("unroll")                                                         \
    for (int s = 0; s < 4; ++s) {                                             \
        f32x4 _a = {0.f, 0.f, 0.f, 0.f};                                      \
        f32x4 _b = {0.f, 0.f, 0.f, 0.f};                                      \
        _a = mfma16(Fb0h, Ah0[s], _a);                                        \
        _b = mfma16(Fb1l, Ah1[s], _b);                                        \
        _a = mfma16(Fb1h, Ah1[s], _a);                                        \
        _b = mfma16(Fb0h, Al0[s], _b);                                        \
        _a = mfma16(Fb0l, Ah0[s], _a);                                        \
        _b = mfma16(Fb1h, Al1[s], _b);                                        \
        PA_[s] = _a; PB_[s] = _b;                                             \
    }                                                                         \
} while (0)

// t-score top-2 update: combine accA+accB then local top2-of-4 + merge
#define VALUU(T) do {                                                         \
    f32x4 _sck = *(const f32x4*)&scl[(T) * 16 + g4];                          \
    int _kb = (T) * 16 + g4;                                                  \
    _Pragma("unroll")                                                         \
    for (int s = 0; s < 4; ++s) {                                             \
        float _p0 = __fadd_rn(PA_[s][0], PB_[s][0]);                          \
        float _p1 = __fadd_rn(PA_[s][1], PB_[s][1]);                          \
        float _p2 = __fadd_rn(PA_[s][2], PB_[s][2]);                          \
        float _p3 = __fadd_rn(PA_[s][3], PB_[s][3]);                          \
        float _s0 = __fmaf_rn(-2.0f, _p0, _sck[0]);                           \
        float _s1 = __fmaf_rn(-2.0f, _p1, _sck[1]);                           \
        float _s2 = __fmaf_rn(-2.0f, _p2, _sck[2]);                           \
        float _s3 = __fmaf_rn(-2.0f, _p3, _sck[3]);                           \
        float _lo1 = fminf(_s0, _s1), _hi1 = fmaxf(_s0, _s1);                 \
        float _lo2 = fminf(_s2, _s3), _hi2 = fmaxf(_s2, _s3);                 \
        int _il1 = (_s1 < _s0) ? 1 : 0;                                       \
        int _il2 = (_s3 < _s2) ? 3 : 2;                                       \
        float _m1p = fminf(_lo1, _lo2);                                       \
        int _ip = (_lo2 < _lo1) ? _il2 : _il1;                                \
        float _m2p = fminf(fmaxf(_lo1, _lo2), fminf(_hi1, _hi2));             \
        m2[s] = fminf(__builtin_amdgcn_fmed3f(_m1p, m1[s], m2[s]), _m2p);     \
        i1[s] = (_m1p < m1[s]) ? (_kb + _ip) : i1[s];                         \
        m1[s] = fminf(m1[s], _m1p);                                           \
    }                                                                         \
} while (0)

// 2-buffer pair (R16/R17-proven): compute e,e+1; stage e+2 (b0), e+3 (b1)
#define ITEV(E) do {                                                          \
    MFMAC();                                                                  \
    STAGE(t0 + (E) + 2, 0);                                                   \
    VMWAIT(4);                                                                \
    DSREAD(1);                                                                \
    VALUU(t0 + (E));                                                          \
} while (0)
#define ITOD(E) do {                                                          \
    MFMAC();                                                                  \
    STAGE(t0 + (E) + 3, 1);                                                   \
    VMWAIT(4);                                                                \
    DSREAD(0);                                                                \
    VALUU(t0 + (E) + 1);                                                      \
} while (0)

__global__ __launch_bounds__(256, 2) void phase1_kernel(
    const float* __restrict__ x, const float* __restrict__ sx,
    const float* __restrict__ sc, const bf16x8* __restrict__ cbf,
    int* __restrict__ idxbuf, int* __restrict__ amb_cnt, int* __restrict__ amb_rows)
{
    __shared__ __align__(16) char ring[4][2][4096]; // [wave][buf][bytes] 32K
    __shared__ float scl[4096];                     // sc staged in LDS 16K
    __shared__ float lm1[64][4], lm2[64][4];        // per-quarter top-2, 3K
    __shared__ int   li1[64][4];

    const int tid  = threadIdx.x;
    const int w    = tid >> 6;
    const int lane = tid & 63;
    const int r = lane & 15, g = lane >> 4;
    const int g4 = g * 4;
    const int wbase = blockIdx.x * 64;              // all 4 waves: same 64 rows
    const int t0 = w * 64;                          // wave's quarter of tiles

    for (int j = tid; j < 1024; j += 256)
        *(float4*)&scl[j * 4] = *(const float4*)&sc[j * 4];
    __syncthreads();

    // x fragments (head+tail) for 4 row-subtiles (row = wbase + s*16 + r)
    bf16x8 Ah0[4], Ah1[4], Al0[4], Al1[4];
    #pragma unroll
    for (int s = 0; s < 4; ++s) {
        const float* xr = x + (size_t)(wbase + s * 16 + r) * D;
        float e0[8], e1[8];
        float4 f0 = *(const float4*)(xr + g * 4);
        float4 f1 = *(const float4*)(xr + 16 + g * 4);
        float4 f2 = *(const float4*)(xr + 32 + g * 4);
        float4 f3 = *(const float4*)(xr + 48 + g * 4);
        e0[0]=f0.x;e0[1]=f0.y;e0[2]=f0.z;e0[3]=f0.w; e0[4]=f1.x;e0[5]=f1.y;e0[6]=f1.z;e0[7]=f1.w;
        e1[0]=f2.x;e1[1]=f2.y;e1[2]=f2.z;e1[3]=f2.w; e1[4]=f3.x;e1[5]=f3.y;e1[6]=f3.z;e1[7]=f3.w;
        #pragma unroll
        for (int j = 0; j < 8; ++j) {
            u16 h0 = f32_to_bf16_raw(e0[j]);
            Ah0[s][j] = (short)h0;
            Al0[s][j] = (short)f32_to_bf16_raw(e0[j] - bf16_raw_to_f32(h0));
            u16 h1 = f32_to_bf16_raw(e1[j]);
            Ah1[s][j] = (short)h1;
            Al1[s][j] = (short)f32_to_bf16_raw(e1[j] - bf16_raw_to_f32(h1));
        }
    }

    float m1[4], m2[4];
    int   i1[4];
    #pragma unroll
    for (int s = 0; s < 4; ++s) { m1[s] = 3.4e38f; m2[s] = 3.4e38f; i1[s] = 0; }

    char* ringbase = &ring[w][0][0];

    bf16x8 Fb0h, Fb1h, Fb0l, Fb1l;
    f32x4  PA_[4], PB_[4];

    // prologue
    VMWAIT(0);                                   // normalize vm counter
    STAGE(t0 + 0, 0); STAGE(t0 + 1, 1);          // 8 outstanding
    VMWAIT(4);                                   // tile 0 landed
    DSREAD(0);                                   // Fb = tile 0

    // main pairs e=0,2,..,60: compute e,e+1; stage e+2,e+3
    #pragma unroll 1
    for (int e = 0; e < 62; e += 2) {
        ITEV(e);
        ITOD(e);
    }
    // after e=60 pair: Fb=tile62, outstanding = stage(63) x4 (in buf1)
    MFMAC(); VMWAIT(0); DSREAD(1); VALUU(t0 + 62);   // tile 62
    MFMAC(); VALUU(t0 + 63);                          // tile 63

    // merge top-2 across the 4 g-groups (codes) -> lanes 0..15 hold final
    #pragma unroll
    for (int s = 0; s < 4; ++s) {
        #pragma unroll
        for (int mm = 16; mm < 64; mm <<= 1) {
            float om1 = __shfl_xor(m1[s], mm, 64);
            float om2 = __shfl_xor(m2[s], mm, 64);
            int   oi1 = __shfl_xor(i1[s], mm, 64);
            float nm2 = fminf(fmaxf(m1[s], om1), fminf(m2[s], om2));
            i1[s] = (om1 < m1[s]) ? oi1 : i1[s];
            m1[s] = fminf(m1[s], om1);
            m2[s] = nm2;
        }
    }
    if (lane < 16) {
        #pragma unroll
        for (int s = 0; s < 4; ++s) {
            int rowin = s * 16 + lane;
            lm1[rowin][w] = m1[s];
            lm2[rowin][w] = m2[s];
            li1[rowin][w] = i1[s];
        }
    }
    __syncthreads();

    // 4-quarter exact top-2 union merge (R15/R17-proven): q asc = k asc;
    // ties -> gap 0 -> ambiguous -> exact_scan resolves first-min exactly
    if (tid < 64) {
        float M1 = lm1[tid][0], M2 = lm2[tid][0];
        int   I1 = li1[tid][0];
        #pragma unroll
        for (int q = 1; q < 4; ++q) {
            float a1 = lm1[tid][q], a2 = lm2[tid][q];
            int   ai = li1[tid][q];
            M2 = __builtin_amdgcn_fmed3f(a1, M1, M2);
            I1 = (a1 < M1) ? ai : I1;
            M1 = fminf(M1, a1);
            M2 = __builtin_amdgcn_fmed3f(a2, M1, M2);
        }
        int orow = wbase + tid;
        idxbuf[orow] = I1;
        float marg = __fmaf_rn(sx[orow], MARG_B, MARG_A);
        if (M2 - M1 <= marg) {
            int slot = atomicAdd(amb_cnt, 1);
            amb_rows[slot] = orow;
        }
    }
}

// ---------- exact rescan of ambiguous rows (reference-exact f32), proven R5 ----------
__global__ __launch_bounds__(256) void exact_scan(
    const float* __restrict__ x, const float* __restrict__ cb,
    const float* __restrict__ sx, const float* __restrict__ sc,
    const int* __restrict__ amb_cnt, const int* __restrict__ amb_rows,
    int* __restrict__ idxbuf)
{
    __shared__ float csT[4][64][64];   // [tz][d][code]
    __shared__ float xsT[64][16];      // [d][row]
    __shared__ float redv[16][64];
    __shared__ int   redi[16][64];
    __shared__ float sxl[16];
    __shared__ int   rowids[16];

    const int tid = threadIdx.x;
    const int cnt = *amb_cnt;
    const int tz = tid >> 6, ty = (tid >> 4) & 3, cx = tid & 15;

    for (int base = blockIdx.x * 16; base < cnt; base += gridDim.x * 16) {
        if (tid < 16) {
            int i = base + tid;
            int rr = (i < cnt) ? amb_rows[i] : amb_rows[base];
            rowids[tid] = rr;
            sxl[tid] = sx[rr];
        }
        __syncthreads();
        {
            int rr = rowids[tid >> 4];
            int dg = tid & 15;
            float4 v = *(const float4*)(x + (size_t)rr * D + dg * 4);
            xsT[dg*4+0][tid>>4] = v.x; xsT[dg*4+1][tid>>4] = v.y;
            xsT[dg*4+2][tid>>4] = v.z; xsT[dg*4+3][tid>>4] = v.w;
        }

        float bv[4]; int bi[4];
        #pragma unroll
        for (int i = 0; i < 4; ++i) { bv[i] = 3.4e38f; bi[i] = 0x7fffffff; }

        for (int st = 0; st < 16; ++st) {
            __syncthreads();
            {
                int code = st * 256 + tid;
                const float4* src = (const float4*)(cb + (size_t)code * D);
                #pragma unroll
                for (int dd = 0; dd < 16; ++dd) {
                    float4 v = src[dd];
                    csT[tid>>6][dd*4+0][tid&63] = v.x; csT[tid>>6][dd*4+1][tid&63] = v.y;
                    csT[tid>>6][dd*4+2][tid&63] = v.z; csT[tid>>6][dd*4+3][tid&63] = v.w;
                }
            }
            __syncthreads();

            float acc[4][4];
            #pragma unroll
            for (int i = 0; i < 4; ++i)
                #pragma unroll
                for (int j = 0; j < 4; ++j) acc[i][j] = 0.0f;

            #pragma unroll 4
            for (int d = 0; d < 64; ++d) {
                float4 xv = *(const float4*)&xsT[d][ty * 4];
                float4 cv = *(const float4*)&csT[tz][d][cx * 4];
                float xr[4] = {xv.x, xv.y, xv.z, xv.w};
                float cc[4] = {cv.x, cv.y, cv.z, cv.w};
                #pragma unroll
                for (int i = 0; i < 4; ++i)
                    #pragma unroll
                    for (int j = 0; j < 4; ++j)
                        acc[i][j] = __fmaf_rn(xr[i], cc[j], acc[i][j]);
            }
            #pragma unroll
            for (int j = 0; j < 4; ++j) {
                int k = st * 256 + tz * 64 + cx * 4 + j;
                float sck = sc[k];
                #pragma unroll
                for (int i = 0; i < 4; ++i) {
                    float tt = __fadd_rn(sxl[ty * 4 + i], sck);
                    float u  = __fmul_rn(2.0f, acc[i][j]);
                    float s  = __fsub_rn(tt, u);
                    if (s < bv[i] || (s == bv[i] && k < bi[i])) { bv[i] = s; bi[i] = k; }
                }
            }
        }

        #pragma unroll
        for (int i = 0; i < 4; ++i) { redv[ty*4+i][tz*16+cx] = bv[i]; redi[ty*4+i][tz*16+cx] = bi[i]; }
        __syncthreads();
        if (tid < 16) {
            float bvv = redv[tid][0]; int bii = redi[tid][0];
            #pragma unroll 8
            for (int i = 1; i < 64; ++i) {
                float v = redv[tid][i]; int k = redi[tid][i];
                if (v < bvv || (v == bvv && k < bii)) { bvv = v; bii = k; }
            }
            idxbuf[rowids[tid]] = bii;
        }
        __syncthreads();
    }
}

// ---------- finalize + loss (R5..R17-proven form) ----------
__global__ __launch_bounds__(256) void finalize_rows(
    const float* __restrict__ x, const float* __restrict__ cb,
    const int* __restrict__ idxbuf,
    float* __restrict__ out_q, float* __restrict__ out_i,
    double* __restrict__ partials, int N)
{
    __shared__ double wsum[4];
    int wid = threadIdx.x >> 6, lane = threadIdx.x & 63;
    int n = blockIdx.x * 4 + wid;

    int idx = idxbuf[n];
    float q  = cb[(size_t)idx * D + lane];
    float xv = x[(size_t)n * D + lane];
    out_q[(size_t)n * D + lane] = q;

    double diff = (double)xv - (double)q;
    double s = diff * diff;
    #pragma unroll
    for (int off = 32; off > 0; off >>= 1) s += __shfl_down(s, off, 64);
    if (lane == 0) { wsum[wid] = s; out_i[n] = (float)idx; }
    __syncthreads();
    if (threadIdx.x == 0) partials[blockIdx.x] = (wsum[0] + wsum[1]) + (wsum[2] + wsum[3]);
}

__global__ __launch_bounds__(256) void loss_kernel(const double* __restrict__ partials,
                                                   int nP, float* __restrict__ out_loss,
                                                   double invND)
{
    __shared__ double red[256];
    double s = 0.0;
    for (int i = threadIdx.x; i < nP; i += 256) s += partials[i];
    red[threadIdx.x] = s;
    __syncthreads();
    #pragma unroll
    for (int step = 128; step > 0; step >>= 1) {
        if ((int)threadIdx.x < step) red[threadIdx.x] += red[threadIdx.x + step];
        __syncthreads();
    }
    if (threadIdx.x == 0) {
        double m = red[0] * invND;
        out_loss[0] = (float)(0.25 * m + m);
    }
}

extern "C" void kernel_launch(void* const* d_in, const int* in_sizes, int n_in,
                              void* d_out, int out_size, void* d_ws, size_t ws_size,
                              hipStream_t stream)
{
    const float* x  = (const float*)d_in[0];
    const float* cb = (const float*)d_in[1];
    const int N = in_sizes[0] / D;   // 65536
    const int K = in_sizes[1] / D;   // 4096

    float* out      = (float*)d_out;
    float* out_q    = out;
    float* out_i    = out + (size_t)N * D;
    float* out_loss = out_i + N;

    char* ws = (char*)d_ws;
    bf16x8* cbf      = (bf16x8*)ws;                         // 1 MB
    size_t off = (size_t)(K / 16) * 4 * 64 * sizeof(bf16x8);
    float*  sx       = (float*)(ws + off);  off += (size_t)N * 4;
    float*  sc       = (float*)(ws + off);  off += (size_t)K * 4;
    int*    idxbuf   = (int*)(ws + off);    off += (size_t)N * 4;
    int*    amb_rows = (int*)(ws + off);    off += (size_t)N * 4;
    double* partials = (double*)(ws + off); off += (size_t)(N / 4) * 8;
    int*    amb_cnt  = (int*)(ws + off);

    prep_kernel<<<272 + K / 16, 256, 0, stream>>>(x, cb, sx, sc, cbf, amb_cnt);
    phase1_kernel<<<N / 64, 256, 0, stream>>>(x, sx, sc, cbf, idxbuf, amb_cnt, amb_rows);
    exact_scan<<<1024, 256, 0, stream>>>(x, cb, sx, sc, amb_cnt, amb_rows, idxbuf);
    finalize_rows<<<N / 4, 256, 0, stream>>>(x, cb, idxbuf, out_q, out_i, partials, N);
    loss_kernel<<<1, 256, 0, stream>>>(partials, N / 4, out_loss,
                                       1.0 / ((double)N * (double)D));
}

// Round 19
// 243.568 us; speedup vs baseline: 1.0643x; 1.0643x over previous
//
#include <hip/hip_runtime.h>

// VQ quantizer: N=65536 rows (D=64) vs K=4096 codes. d_out = FLOAT32
// [x_quantized N*D][indices N][loss 1].
//
// Round-19: PURE REVERT to R14 — the measured best (243.7us total; phase1
// 127.4us, VGPR=120, no spills, 2 blocks/CU). R15-R18 explored occupancy
// (3 blocks/CU), LDS diets, and MFMA chain-splitting: all neutral-to-worse.
// Swapped-operand MFMA (mfma(cb, x, acc)): lane holds 4 codes of ONE row ->
// top-2 state = 12 VGPR. Split-K wave pairs; t-score + med3 top-2; margin
// gap-test; exact f32-chain rescan for ambiguous rows.

#define D  64
#define NT 256          // K/16 code tiles

typedef unsigned short u16;
typedef short bf16x8 __attribute__((ext_vector_type(8)));
typedef float f32x4  __attribute__((ext_vector_type(4)));

#define VMWAIT_(n) asm volatile("s_waitcnt vmcnt(" #n ")" ::: "memory")
#define VMWAIT(n) VMWAIT_(n)

__device__ __forceinline__ u16 f32_to_bf16_raw(float f) {
    union { float f; unsigned u; } v; v.f = f;
    unsigned u = v.u;
    u += 0x7FFFu + ((u >> 16) & 1u);   // RNE
    return (u16)(u >> 16);
}
__device__ __forceinline__ float bf16_raw_to_f32(u16 h) {
    union { unsigned u; float f; } v; v.u = ((unsigned)h) << 16;
    return v.f;
}
__device__ __forceinline__ f32x4 mfma16(bf16x8 a, bf16x8 b, f32x4 c) {
    return __builtin_amdgcn_mfma_f32_16x16x32_bf16(a, b, c, 0, 0, 0);
}

// ---------- numpy-exact row sum of squares (pairwise n=64), proven R3 ----------
__device__ __forceinline__ float np_pairwise_sumsq_64(const float* p) {
    float r[8];
    #pragma unroll
    for (int j = 0; j < 8; ++j) r[j] = __fmul_rn(p[j], p[j]);
    #pragma unroll
    for (int i = 8; i < 64; i += 8) {
        #pragma unroll
        for (int j = 0; j < 8; ++j)
            r[j] = __fadd_rn(r[j], __fmul_rn(p[i + j], p[i + j]));
    }
    float t0 = __fadd_rn(r[0], r[1]);
    float t1 = __fadd_rn(r[2], r[3]);
    float t2 = __fadd_rn(r[4], r[5]);
    float t3 = __fadd_rn(r[6], r[7]);
    return __fadd_rn(__fadd_rn(t0, t1), __fadd_rn(t2, t3));
}

// ---------- fused prep: rowsumsq(x|cb) + pack + amb_cnt zeroing ----------
__global__ __launch_bounds__(256) void prep_kernel(const float* __restrict__ x,
                                                   const float* __restrict__ cb,
                                                   float* __restrict__ sx,
                                                   float* __restrict__ sc,
                                                   bf16x8* __restrict__ cbf,
                                                   int* __restrict__ amb_cnt) {
    int b = blockIdx.x;
    if (b == 0 && threadIdx.x == 0) *amb_cnt = 0;
    if (b < 272) {
        const float* a = (b < 256) ? x : cb;
        float* o = (b < 256) ? sx : sc;
        int r0 = (b < 256) ? b * 256 : (b - 256) * 256;
        int r = r0 + threadIdx.x;
        float buf[64];
        const float4* p = (const float4*)(a + (size_t)r * D);
        #pragma unroll
        for (int i = 0; i < 16; ++i) {
            float4 v = p[i];
            buf[4*i] = v.x; buf[4*i+1] = v.y; buf[4*i+2] = v.z; buf[4*i+3] = v.w;
        }
        o[r] = np_pairwise_sumsq_64(buf);
    } else {
        // pack codebook tile t: head/tail bf16 fragments (layout proven R5)
        int t = b - 272;
        int tid = threadIdx.x;
        int lane = tid & 63;
        int ks = (tid >> 6) & 1;
        int hl = tid >> 7;
        int code = t * 16 + (lane & 15);
        int g = lane >> 4;
        bf16x8 v;
        #pragma unroll
        for (int j = 0; j < 8; ++j) {
            int d = ks * 32 + g * 4 + (j & 3) + 16 * (j >> 2);
            float val = cb[(size_t)code * D + d];
            u16 h = f32_to_bf16_raw(val);
            if (hl) {
                float resid = val - bf16_raw_to_f32(h);   // exact (Sterbenz)
                h = f32_to_bf16_raw(resid);
            }
            v[j] = (short)h;
        }
        cbf[((size_t)t * 4 + hl * 2 + ks) * 64 + lane] = v;
    }
}

// ---------- phase 1: swapped-operand split-bf16 MFMA, top-2 on t-scores ----------
// t[k] = fmaf(-2, dot_mfma, sc[k]); gap > MARG_A + sx*MARG_B proves winner.
#define MARG_A 1.6e-5f
#define MARG_B 6.5e-7f

#define STAGE(T, BUF) do {                                                    \
    const char* _src = (const char*)cbf + (size_t)(T) * 4096 + lane * 16;     \
    char* _dst = ringbase + (BUF) * 4096 + lane * 16;                         \
    __builtin_amdgcn_global_load_lds((const __attribute__((address_space(1))) unsigned int*)(_src),        (__attribute__((address_space(3))) unsigned int*)(_dst),        16, 0, 0); \
    __builtin_amdgcn_global_load_lds((const __attribute__((address_space(1))) unsigned int*)(_src + 1024), (__attribute__((address_space(3))) unsigned int*)(_dst + 1024), 16, 0, 0); \
    __builtin_amdgcn_global_load_lds((const __attribute__((address_space(1))) unsigned int*)(_src + 2048), (__attribute__((address_space(3))) unsigned int*)(_dst + 2048), 16, 0, 0); \
    __builtin_amdgcn_global_load_lds((const __attribute__((address_space(1))) unsigned int*)(_src + 3072), (__attribute__((address_space(3))) unsigned int*)(_dst + 3072), 16, 0, 0); \
} while (0)

#define DSREAD(BUF) do {                                                      \
    const bf16x8* _bfr = (const bf16x8*)(ringbase + (BUF) * 4096);            \
    Fb0h = _bfr[lane]; Fb1h = _bfr[64 + lane];                                \
    Fb0l = _bfr[128 + lane]; Fb1l = _bfr[192 + lane];                         \
} while (0)

// 4 subtiles x 6-MFMA chains; SWAPPED operand order: A=codebook frags (LDS),
// B=x frags (regs). Same product set as R5..R13 (k-map symmetry proven by
// R5's pass); output: lane holds 4 CODES (g*4+q) of row (lane&15).
#define MFMAC() do {                                                          \
    _Pragma("unroll")                                                         \
    for (int s = 0; s < 4; ++s) {                                             \
        f32x4 _a = {0.f, 0.f, 0.f, 0.f};                                      \
        _a = mfma16(Fb0h, Ah0[s], _a);                                        \
        _a = mfma16(Fb1h, Ah1[s], _a);                                        \
        _a = mfma16(Fb0l, Ah0[s], _a);                                        \
        _a = mfma16(Fb1l, Ah1[s], _a);                                        \
        _a = mfma16(Fb0h, Al0[s], _a);                                        \
        _a = mfma16(Fb1h, Al1[s], _a);                                        \
        P[s] = _a;                                                            \
    }                                                                         \
} while (0)

// per-tile score update: 4 codes x 1 row per lane per subtile.
// local top2-of-4 (first-min index) then exact streaming top-2 merge.
#define VALUU(T) do {                                                         \
    f32x4 _sck = *(const f32x4*)&scl[(T) * 16 + g4];                          \
    int _kb = (T) * 16 + g4;                                                  \
    _Pragma("unroll")                                                         \
    for (int s = 0; s < 4; ++s) {                                             \
        float _s0 = __fmaf_rn(-2.0f, P[s][0], _sck[0]);                       \
        float _s1 = __fmaf_rn(-2.0f, P[s][1], _sck[1]);                       \
        float _s2 = __fmaf_rn(-2.0f, P[s][2], _sck[2]);                       \
        float _s3 = __fmaf_rn(-2.0f, P[s][3], _sck[3]);                       \
        float _lo1 = fminf(_s0, _s1), _hi1 = fmaxf(_s0, _s1);                 \
        float _lo2 = fminf(_s2, _s3), _hi2 = fmaxf(_s2, _s3);                 \
        int _il1 = (_s1 < _s0) ? 1 : 0;                                       \
        int _il2 = (_s3 < _s2) ? 3 : 2;                                       \
        float _m1p = fminf(_lo1, _lo2);                                       \
        int _ip = (_lo2 < _lo1) ? _il2 : _il1;                                \
        float _m2p = fminf(fmaxf(_lo1, _lo2), fminf(_hi1, _hi2));             \
        m2[s] = fminf(__builtin_amdgcn_fmed3f(_m1p, m1[s], m2[s]), _m2p);     \
        i1[s] = (_m1p < m1[s]) ? (_kb + _ip) : i1[s];                         \
        m1[s] = fminf(m1[s], _m1p);                                           \
    }                                                                         \
} while (0)

// iter: mfma(t) | stage(t+3) | wait(t+1) | dsread(t+1) | valu(t)
#define ITER(I, BS, BR) do {                                                  \
    MFMAC();                                                                  \
    STAGE(t0 + (I) + 3, BS);                                                  \
    VMWAIT(8);                                                                \
    DSREAD(BR);                                                               \
    VALUU(t0 + (I));                                                          \
} while (0)

__global__ __launch_bounds__(256, 2) void phase1_kernel(
    const float* __restrict__ x, const float* __restrict__ sx,
    const float* __restrict__ sc, const bf16x8* __restrict__ cbf,
    int* __restrict__ idxbuf, int* __restrict__ amb_cnt, int* __restrict__ amb_rows)
{
    __shared__ __align__(16) char ring[4][3][4096];  // [wave][buf][bytes] 48K
    __shared__ float scl[4096];                      // sc staged in LDS 16K
    __shared__ float lm1[128][2], lm2[128][2];
    __shared__ int   li1[128][2];

    const int tid  = threadIdx.x;
    const int w    = tid >> 6;
    const int lane = tid & 63;
    const int r = lane & 15, g = lane >> 4;
    const int g4 = g * 4;
    const int half = w & 1;           // which 128 code-tiles this wave scans
    const int rowg = w >> 1;          // which 64-row group
    const int wbase = blockIdx.x * 128 + rowg * 64;

    for (int j = tid; j < 1024; j += 256)
        *(float4*)&scl[j * 4] = *(const float4*)&sc[j * 4];
    __syncthreads();

    // x fragments (head+tail) for 4 row-subtiles (row = wbase + s*16 + r)
    bf16x8 Ah0[4], Ah1[4], Al0[4], Al1[4];
    #pragma unroll
    for (int s = 0; s < 4; ++s) {
        const float* xr = x + (size_t)(wbase + s * 16 + r) * D;
        float e0[8], e1[8];
        float4 f0 = *(const float4*)(xr + g * 4);
        float4 f1 = *(const float4*)(xr + 16 + g * 4);
        float4 f2 = *(const float4*)(xr + 32 + g * 4);
        float4 f3 = *(const float4*)(xr + 48 + g * 4);
        e0[0]=f0.x;e0[1]=f0.y;e0[2]=f0.z;e0[3]=f0.w; e0[4]=f1.x;e0[5]=f1.y;e0[6]=f1.z;e0[7]=f1.w;
        e1[0]=f2.x;e1[1]=f2.y;e1[2]=f2.z;e1[3]=f2.w; e1[4]=f3.x;e1[5]=f3.y;e1[6]=f3.z;e1[7]=f3.w;
        #pragma unroll
        for (int j = 0; j < 8; ++j) {
            u16 h0 = f32_to_bf16_raw(e0[j]);
            Ah0[s][j] = (short)h0;
            Al0[s][j] = (short)f32_to_bf16_raw(e0[j] - bf16_raw_to_f32(h0));
            u16 h1 = f32_to_bf16_raw(e1[j]);
            Ah1[s][j] = (short)h1;
            Al1[s][j] = (short)f32_to_bf16_raw(e1[j] - bf16_raw_to_f32(h1));
        }
    }

    float m1[4], m2[4];
    int   i1[4];
    #pragma unroll
    for (int s = 0; s < 4; ++s) { m1[s] = 3.4e38f; m2[s] = 3.4e38f; i1[s] = 0; }

    const int t0 = half * 128;
    char* ringbase = &ring[w][0][0];

    bf16x8 Fb0h, Fb1h, Fb0l, Fb1l;
    f32x4  P[4];

    // prologue
    VMWAIT(0);                                   // normalize vm counter
    STAGE(t0 + 0, 0); STAGE(t0 + 1, 1); STAGE(t0 + 2, 2);   // 12 outstanding
    VMWAIT(8);                                   // tile 0 landed
    DSREAD(0);                                   // Fb = tile 0

    // main loop: tiles 0..122 (unroll-3 buffer pattern), stages up to 125
    #pragma unroll 1
    for (int i = 0; i < 123; i += 3) {
        ITER(i + 0, 0, 1);
        ITER(i + 1, 1, 2);
        ITER(i + 2, 2, 0);
    }
    ITER(123, 0, 1);                              // stages 126, reads 124
    ITER(124, 1, 2);                              // stages 127, reads 125
    // epilogue (tiles 125..127)
    MFMAC(); VMWAIT(4); DSREAD(0); VALUU(t0 + 125);
    MFMAC(); VMWAIT(0); DSREAD(1); VALUU(t0 + 126);
    MFMAC(); VALUU(t0 + 127);

    // merge top-2 across the 4 g-groups (codes) -> lanes 0..15 hold final
    #pragma unroll
    for (int s = 0; s < 4; ++s) {
        #pragma unroll
        for (int mm = 16; mm < 64; mm <<= 1) {
            float om1 = __shfl_xor(m1[s], mm, 64);
            float om2 = __shfl_xor(m2[s], mm, 64);
            int   oi1 = __shfl_xor(i1[s], mm, 64);
            float nm2 = fminf(fmaxf(m1[s], om1), fminf(m2[s], om2));
            i1[s] = (om1 < m1[s]) ? oi1 : i1[s];
            m1[s] = fminf(m1[s], om1);
            m2[s] = nm2;
        }
    }
    if (lane < 16) {
        #pragma unroll
        for (int s = 0; s < 4; ++s) {
            int rowin = rowg * 64 + s * 16 + lane;
            lm1[rowin][half] = m1[s];
            lm2[rowin][half] = m2[s];
            li1[rowin][half] = i1[s];
        }
    }
    __syncthreads();

    // cross-half merge: exact top-2 of union; tie -> lower half (first-min)
    if (tid < 128) {
        float a1 = lm1[tid][0], b1 = lm1[tid][1];
        float a2 = lm2[tid][0], b2 = lm2[tid][1];
        int   ia = li1[tid][0], ib = li1[tid][1];
        float m1f = fminf(a1, b1);
        float m2f = fminf(fmaxf(a1, b1), fminf(a2, b2));
        int   i1f = (b1 < a1) ? ib : ia;
        int orow = blockIdx.x * 128 + tid;
        idxbuf[orow] = i1f;
        float marg = __fmaf_rn(sx[orow], MARG_B, MARG_A);
        if (m2f - m1f <= marg) {
            int slot = atomicAdd(amb_cnt, 1);
            amb_rows[slot] = orow;
        }
    }
}

// ---------- exact rescan of ambiguous rows (reference-exact f32), proven R5 ----------
__global__ __launch_bounds__(256) void exact_scan(
    const float* __restrict__ x, const float* __restrict__ cb,
    const float* __restrict__ sx, const float* __restrict__ sc,
    const int* __restrict__ amb_cnt, const int* __restrict__ amb_rows,
    int* __restrict__ idxbuf)
{
    __shared__ float csT[4][64][64];   // [tz][d][code]
    __shared__ float xsT[64][16];      // [d][row]
    __shared__ float redv[16][64];
    __shared__ int   redi[16][64];
    __shared__ float sxl[16];
    __shared__ int   rowids[16];

    const int tid = threadIdx.x;
    const int cnt = *amb_cnt;
    const int tz = tid >> 6, ty = (tid >> 4) & 3, cx = tid & 15;

    for (int base = blockIdx.x * 16; base < cnt; base += gridDim.x * 16) {
        if (tid < 16) {
            int i = base + tid;
            int rr = (i < cnt) ? amb_rows[i] : amb_rows[base];
            rowids[tid] = rr;
            sxl[tid] = sx[rr];
        }
        __syncthreads();
        {
            int rr = rowids[tid >> 4];
            int dg = tid & 15;
            float4 v = *(const float4*)(x + (size_t)rr * D + dg * 4);
            xsT[dg*4+0][tid>>4] = v.x; xsT[dg*4+1][tid>>4] = v.y;
            xsT[dg*4+2][tid>>4] = v.z; xsT[dg*4+3][tid>>4] = v.w;
        }

        float bv[4]; int bi[4];
        #pragma unroll
        for (int i = 0; i < 4; ++i) { bv[i] = 3.4e38f; bi[i] = 0x7fffffff; }

        for (int st = 0; st < 16; ++st) {
            __syncthreads();
            {
                int code = st * 256 + tid;
                const float4* src = (const float4*)(cb + (size_t)code * D);
                #pragma unroll
                for (int dd = 0; dd < 16; ++dd) {
                    float4 v = src[dd];
                    csT[tid>>6][dd*4+0][tid&63] = v.x; csT[tid>>6][dd*4+1][tid&63] = v.y;
                    csT[tid>>6][dd*4+2][tid&63] = v.z; csT[tid>>6][dd*4+3][tid&63] = v.w;
                }
            }
            __syncthreads();

            float acc[4][4];
            #pragma unroll
            for (int i = 0; i < 4; ++i)
                #pragma unroll
                for (int j = 0; j < 4; ++j) acc[i][j] = 0.0f;

            #pragma unroll 4
            for (int d = 0; d < 64; ++d) {
                float4 xv = *(const float4*)&xsT[d][ty * 4];
                float4 cv = *(const float4*)&csT[tz][d][cx * 4];
                float xr[4] = {xv.x, xv.y, xv.z, xv.w};
                float cc[4] = {cv.x, cv.y, cv.z, cv.w};
                #pragma unroll
                for (int i = 0; i < 4; ++i)
                    #pragma unroll
                    for (int j = 0; j < 4; ++j)
                        acc[i][j] = __fmaf_rn(xr[i], cc[j], acc[i][j]);
            }
            #pragma unroll
            for (int j = 0; j < 4; ++j) {
                int k = st * 256 + tz * 64 + cx * 4 + j;
                float sck = sc[k];
                #pragma unroll
                for (int i = 0; i < 4; ++i) {
                    float tt = __fadd_rn(sxl[ty * 4 + i], sck);
                    float u  = __fmul_rn(2.0f, acc[i][j]);
                    float s  = __fsub_rn(tt, u);
                    if (s < bv[i] || (s == bv[i] && k < bi[i])) { bv[i] = s; bi[i] = k; }
                }
            }
        }

        #pragma unroll
        for (int i = 0; i < 4; ++i) { redv[ty*4+i][tz*16+cx] = bv[i]; redi[ty*4+i][tz*16+cx] = bi[i]; }
        __syncthreads();
        if (tid < 16) {
            float bvv = redv[tid][0]; int bii = redi[tid][0];
            #pragma unroll 8
            for (int i = 1; i < 64; ++i) {
                float v = redv[tid][i]; int k = redi[tid][i];
                if (v < bvv || (v == bvv && k < bii)) { bvv = v; bii = k; }
            }
            idxbuf[rowids[tid]] = bii;
        }
        __syncthreads();
    }
}

// ---------- finalize + loss (R5..R13-proven form) ----------
__global__ __launch_bounds__(256) void finalize_rows(
    const float* __restrict__ x, const float* __restrict__ cb,
    const int* __restrict__ idxbuf,
    float* __restrict__ out_q, float* __restrict__ out_i,
    double* __restrict__ partials, int N)
{
    __shared__ double wsum[4];
    int wid = threadIdx.x >> 6, lane = threadIdx.x & 63;
    int n = blockIdx.x * 4 + wid;

    int idx = idxbuf[n];
    float q  = cb[(size_t)idx * D + lane];
    float xv = x[(size_t)n * D + lane];
    out_q[(size_t)n * D + lane] = q;

    double diff = (double)xv - (double)q;
    double s = diff * diff;
    #pragma unroll
    for (int off = 32; off > 0; off >>= 1) s += __shfl_down(s, off, 64);
    if (lane == 0) { wsum[wid] = s; out_i[n] = (float)idx; }
    __syncthreads();
    if (threadIdx.x == 0) partials[blockIdx.x] = (wsum[0] + wsum[1]) + (wsum[2] + wsum[3]);
}

__global__ __launch_bounds__(256) void loss_kernel(const double* __restrict__ partials,
                                                   int nP, float* __restrict__ out_loss,
                                                   double invND)
{
    __shared__ double red[256];
    double s = 0.0;
    for (int i = threadIdx.x; i < nP; i += 256) s += partials[i];
    red[threadIdx.x] = s;
    __syncthreads();
    #pragma unroll
    for (int step = 128; step > 0; step >>= 1) {
        if ((int)threadIdx.x < step) red[threadIdx.x] += red[threadIdx.x + step];
        __syncthreads();
    }
    if (threadIdx.x == 0) {
        double m = red[0] * invND;
        out_loss[0] = (float)(0.25 * m + m);
    }
}

extern "C" void kernel_launch(void* const* d_in, const int* in_sizes, int n_in,
                              void* d_out, int out_size, void* d_ws, size_t ws_size,
                              hipStream_t stream)
{
    const float* x  = (const float*)d_in[0];
    const float* cb = (const float*)d_in[1];
    const int N = in_sizes[0] / D;   // 65536
    const int K = in_sizes[1] / D;   // 4096

    float* out      = (float*)d_out;
    float* out_q    = out;
    float* out_i    = out + (size_t)N * D;
    float* out_loss = out_i + N;

    char* ws = (char*)d_ws;
    bf16x8* cbf      = (bf16x8*)ws;                         // 1 MB
    size_t off = (size_t)(K / 16) * 4 * 64 * sizeof(bf16x8);
    float*  sx       = (float*)(ws + off);  off += (size_t)N * 4;
    float*  sc       = (float*)(ws + off);  off += (size_t)K * 4;
    int*    idxbuf   = (int*)(ws + off);    off += (size_t)N * 4;
    int*    amb_rows = (int*)(ws + off);    off += (size_t)N * 4;
    double* partials = (double*)(ws + off); off += (size_t)(N / 4) * 8;
    int*    amb_cnt  = (int*)(ws + off);

    prep_kernel<<<272 + K / 16, 256, 0, stream>>>(x, cb, sx, sc, cbf, amb_cnt);
    phase1_kernel<<<N / 128, 256, 0, stream>>>(x, sx, sc, cbf, idxbuf, amb_cnt, amb_rows);
    exact_scan<<<1024, 256, 0, stream>>>(x, cb, sx, sc, amb_cnt, amb_rows, idxbuf);
    finalize_rows<<<N / 4, 256, 0, stream>>>(x, cb, idxbuf, out_q, out_i, partials, N);
    loss_kernel<<<1, 256, 0, stream>>>(partials, N / 4, out_loss,
                                       1.0 / ((double)N * (double)D));
}